// Round 5
// baseline (235.895 us; speedup 1.0000x reference)
//
#include <hip/hip_runtime.h>
#include <cstddef>

// Problem constants
#define B_TOT   256
#define IN_CAPS 1152
#define KDIM    8
#define NJ      10
#define ND      16
#define JD      160               // NJ*ND
#define WSTRIDE (NJ*KDIM*ND)      // 1280 floats per input capsule i

// Tiling: thread = (i_par, j, dq). 8 i-groups x 10 j x 4 d-quads = 320 threads
// (5 waves). BB=4 batches share every W load (dwordx4, 16 B/lane). 2 i per
// thread per chunk -> 16 outstanding dwordx4 W loads for latency hiding.
// grid = (256/BB)*ISPLIT = 512 blocks = 2 independent blocks/CU: one block's
// softmax barrier is covered by the other block's compute.
#define BB      4
#define ISPLIT  8                 // isp == blockIdx&7 == XCD id
#define IRANGE  (IN_CAPS/ISPLIT)  // 144
#define CI      16                // i per chunk (= IPAR * 2)
#define IPAR    8
#define NTHREADS 320
#define NCHUNK  (IRANGE/CI)       // 9
#define LPAD    12                // logit row padded 10 -> 12 (16B-aligned)
#define EPSQ    1e-7f

__device__ __forceinline__ float dot4(float4 a, float4 b) {
    return a.x*b.x + a.y*b.y + a.z*b.z + a.w*b.w;
}

// One routing iteration: s_out[b,j,d] += sum_i c[b,i,j] * u_hat[b,i,j,d]
// u_hat recomputed from x (LDS, staged once) and W (L2-resident per XCD slice).
// ITER==1: c uniform = 0.1 (softmax of zeros), premultiplied at the end;
//          ZERO barriers in the main loop.
// ITER==2: logits = u_hat . v1,  v1 = squash(s1)  (squash fused in head)
// ITER==3: logits = u_hat . (v1+v2)  (linearity of the b-update in v);
//          ONE barrier per chunk (own logit kept in-register; parity-double-
//          buffered logit rows make next chunk's writes race-free).
// NOTE: no min-waves arg in __launch_bounds__ (r1/r2: (640,5) forced VGPR=48
// + scratch spills, WRITE_SIZE 16-21 MB).
template<int ITER>
__global__ __launch_bounds__(NTHREADS)
void iter_kernel(const float* __restrict__ x, const float* __restrict__ Wt,
                 const float* __restrict__ s1, const float* __restrict__ s2,
                 float* __restrict__ s_out)
{
    const int g   = blockIdx.x >> 3;       // b-group 0..63
    const int isp = blockIdx.x & 7;        // i-split == XCD id (round-robin)
    const int b0  = g * BB;
    const int i_begin = isp * IRANGE;

    const int t = threadIdx.x;
    const int i_par = t / 40;              // 0..7
    const int r  = t - i_par * 40;
    const int j  = r >> 2;                 // 0..9
    const int dq = r & 3;                  // 0..3 (owns d = dq*4..dq*4+3)

    __shared__ float x_lds[BB][IRANGE][KDIM];      // 18.0 KB (staged once)
    __shared__ float logit_lds[2][BB][CI][LPAD];   // 6.0 KB (parity dbuf)
    __shared__ float s_red[BB][JD];                // 2.5 KB

    // head: v for this thread's (j, dq) — fused squash of previous iteration(s)
    float4 vs[BB];
    if constexpr (ITER >= 2) {
        #pragma unroll
        for (int bb = 0; bb < BB; ++bb) {
            const float4 a = *(const float4*)(s1 + (size_t)(b0 + bb) * JD + j * ND + dq * 4);
            float q2 = dot4(a, a);
            q2 += __shfl_xor(q2, 1);       // sum over the 4-lane d-quad (16 d)
            q2 += __shfl_xor(q2, 2);
            const float sc = q2 / (1.f + q2) / sqrtf(q2 + EPSQ);
            vs[bb] = make_float4(a.x * sc, a.y * sc, a.z * sc, a.w * sc);
            if constexpr (ITER == 3) {
                const float4 bv = *(const float4*)(s2 + (size_t)(b0 + bb) * JD + j * ND + dq * 4);
                float r2 = dot4(bv, bv);
                r2 += __shfl_xor(r2, 1);
                r2 += __shfl_xor(r2, 2);
                const float sc2 = r2 / (1.f + r2) / sqrtf(r2 + EPSQ);
                vs[bb].x += bv.x * sc2; vs[bb].y += bv.y * sc2;
                vs[bb].z += bv.z * sc2; vs[bb].w += bv.w * sc2;
            }
        }
    }

    // stage entire x slice: BB * 288 float4, contiguous & coalesced
    {
        const int NF = (IRANGE * KDIM) / 4;    // 288 float4 per batch
        for (int idx = t; idx < BB * NF; idx += NTHREADS) {
            const int bb = idx / NF;
            const int f  = idx - bb * NF;
            ((float4*)&x_lds[bb][0][0])[f] =
                ((const float4*)(x + (size_t)(b0 + bb) * IN_CAPS * KDIM
                                   + (size_t)i_begin * KDIM))[f];
        }
    }
    __syncthreads();

    float4 sacc[BB];
    #pragma unroll
    for (int bb = 0; bb < BB; ++bb) sacc[bb] = make_float4(0.f, 0.f, 0.f, 0.f);

    // W base for this thread's first capsule (i = i_begin + i_par*2)
    const float* wpc = Wt + (size_t)((i_begin + i_par * 2) * NJ + j) * (KDIM * ND) + dq * 4;

    for (int c = 0; c < NCHUNK; ++c) {
        const int p = c & 1;
        float4 u[2][BB];
        float  lgr[2][BB];

        #pragma unroll
        for (int ii = 0; ii < 2; ++ii) {
            const int il = c * CI + i_par * 2 + ii;       // 0..143 (x_lds index)
            const float* wp = wpc + (size_t)ii * WSTRIDE;
            // 8 independent dwordx4 W loads (one capsule's (j,:) row for this dq)
            float4 w[KDIM];
            #pragma unroll
            for (int k = 0; k < KDIM; ++k)
                w[k] = *(const float4*)(wp + k * ND);
            #pragma unroll
            for (int bb = 0; bb < BB; ++bb) {
                float xs[KDIM];
                *(float4*)&xs[0] = *(const float4*)&x_lds[bb][il][0];   // ds_read_b128
                *(float4*)&xs[4] = *(const float4*)&x_lds[bb][il][4];   // ds_read_b128
                float4 uu = make_float4(0.f, 0.f, 0.f, 0.f);
                #pragma unroll
                for (int k = 0; k < KDIM; ++k) {
                    uu.x += xs[k] * w[k].x; uu.y += xs[k] * w[k].y;
                    uu.z += xs[k] * w[k].z; uu.w += xs[k] * w[k].w;
                }
                u[ii][bb] = uu;
                if constexpr (ITER >= 2) {
                    float lg = dot4(uu, vs[bb]);
                    lg += __shfl_xor(lg, 1);   // reduce over the 4-lane d-quad
                    lg += __shfl_xor(lg, 2);   // (identical value in all 4 lanes)
                    lgr[ii][bb] = lg;
                    if (dq == 0) logit_lds[p][bb][i_par * 2 + ii][j] = lg;
                }
            }
        }

        if constexpr (ITER == 1) {
            // uniform c: just accumulate. NO barriers at all in this loop.
            #pragma unroll
            for (int ii = 0; ii < 2; ++ii)
                #pragma unroll
                for (int bb = 0; bb < BB; ++bb) {
                    sacc[bb].x += u[ii][bb].x; sacc[bb].y += u[ii][bb].y;
                    sacc[bb].z += u[ii][bb].z; sacc[bb].w += u[ii][bb].w;
                }
        } else {
            __syncthreads();   // the ONLY barrier per chunk
            // private softmax: own logit is in-register; row gives max & sum.
            // Safe vs next chunk: it writes the OTHER parity buffer.
            #pragma unroll
            for (int ii = 0; ii < 2; ++ii) {
                #pragma unroll
                for (int bb = 0; bb < BB; ++bb) {
                    const float* row = &logit_lds[p][bb][i_par * 2 + ii][0];
                    const float4 ra = *(const float4*)(row);
                    const float4 rb = *(const float4*)(row + 4);
                    const float2 rc = *(const float2*)(row + 8);
                    const float m = fmaxf(
                        fmaxf(fmaxf(ra.x, ra.y), fmaxf(ra.z, ra.w)),
                        fmaxf(fmaxf(fmaxf(rb.x, rb.y), fmaxf(rb.z, rb.w)),
                              fmaxf(rc.x, rc.y)));
                    const float ssum =
                        __expf(ra.x - m) + __expf(ra.y - m) + __expf(ra.z - m) + __expf(ra.w - m) +
                        __expf(rb.x - m) + __expf(rb.y - m) + __expf(rb.z - m) + __expf(rb.w - m) +
                        __expf(rc.x - m) + __expf(rc.y - m);
                    const float cc = __fdividef(__expf(lgr[ii][bb] - m), ssum);
                    sacc[bb].x += cc * u[ii][bb].x; sacc[bb].y += cc * u[ii][bb].y;
                    sacc[bb].z += cc * u[ii][bb].z; sacc[bb].w += cc * u[ii][bb].w;
                }
            }
        }

        wpc += (size_t)CI * WSTRIDE;
    }

    // block reduction over the 8 i_par groups via LDS atomics, then global
    for (int e = t; e < BB * JD; e += NTHREADS) ((float*)s_red)[e] = 0.f;
    __syncthreads();
    #pragma unroll
    for (int bb = 0; bb < BB; ++bb) {
        atomicAdd(&s_red[bb][j * ND + dq * 4 + 0], sacc[bb].x);
        atomicAdd(&s_red[bb][j * ND + dq * 4 + 1], sacc[bb].y);
        atomicAdd(&s_red[bb][j * ND + dq * 4 + 2], sacc[bb].z);
        atomicAdd(&s_red[bb][j * ND + dq * 4 + 3], sacc[bb].w);
    }
    __syncthreads();
    const float premul = (ITER == 1) ? 0.1f : 1.0f;   // softmax(zeros) over 10 caps
    for (int e = t; e < BB * JD; e += NTHREADS) {
        const int bb = e / JD;
        const int jd = e - bb * JD;
        unsafeAtomicAdd(&s_out[(size_t)(b0 + bb) * JD + jd], s_red[bb][jd] * premul);
    }
}

// final squash per (b,j): v = s * s2/(1+s2)/sqrt(s2+eps); 16-lane shuffle reduction.
__global__ __launch_bounds__(256)
void squash_kernel(const float* __restrict__ s, float* __restrict__ out)
{
    const int idx = blockIdx.x * 256 + threadIdx.x;   // grid 160 -> exactly 40960
    const float sv = s[idx];
    float sq = sv * sv;
    sq += __shfl_xor(sq, 1);
    sq += __shfl_xor(sq, 2);
    sq += __shfl_xor(sq, 4);
    sq += __shfl_xor(sq, 8);    // sum over the 16 d-lanes (16-aligned in wave)
    const float scale = sq / (1.0f + sq) / sqrtf(sq + EPSQ);
    out[idx] = sv * scale;
}

extern "C" void kernel_launch(void* const* d_in, const int* in_sizes, int n_in,
                              void* d_out, int out_size, void* d_ws, size_t ws_size,
                              hipStream_t stream)
{
    const float* x  = (const float*)d_in[0];   // [256,1152,8]
    const float* Wt = (const float*)d_in[1];   // [1152,10,8,16]
    float* out = (float*)d_out;                // [256,10,16]
    float* s1  = (float*)d_ws;                 // 40960 floats each
    float* s2  = s1 + (size_t)B_TOT * JD;
    float* s3  = s2 + (size_t)B_TOT * JD;

    // ws is re-poisoned before every launch: zero the three s accumulators (480 KB)
    hipMemsetAsync(d_ws, 0, 3 * (size_t)B_TOT * JD * sizeof(float), stream);

    dim3 grid((B_TOT / BB) * ISPLIT), blk(NTHREADS);   // 512 blocks x 320 thr

    iter_kernel<1><<<grid, blk, 0, stream>>>(x, Wt, nullptr, nullptr, s1);
    iter_kernel<2><<<grid, blk, 0, stream>>>(x, Wt, s1, nullptr, s2);
    iter_kernel<3><<<grid, blk, 0, stream>>>(x, Wt, s1, s2, s3);
    squash_kernel<<<dim3((B_TOT * JD) / 256), dim3(256), 0, stream>>>(s3, out);
}